// Round 1
// baseline (2391.503 us; speedup 1.0000x reference)
//
#include <hip/hip_runtime.h>
#include <math.h>

// Problem constants
#define BB 2
#define NN 4096
#define DD 1024
#define HH 16
#define HKV 4
#define DHH 64
#define BNT 8192   // B*N

// ---------------------------------------------------------------------------
// Generic 128x128 tiled GEMM, fp32 inputs, templated accumulator (float/double)
// C[M,N] = A[M,K] @ B[K,N], all row-major with explicit leading dims.
// Requires M%128==0, N%128==0, K%8==0.
// ---------------------------------------------------------------------------
template <typename AccT>
__global__ __launch_bounds__(256)
void gemm_tile(const float* __restrict__ A, const float* __restrict__ Bm,
               float* __restrict__ C, int K, int lda, int ldb, int ldc)
{
    __shared__ float As[8][128];
    __shared__ float Bs[8][128];
    const int tid = threadIdx.x;
    const int bx = blockIdx.x, by = blockIdx.y;
    const int arow = tid >> 1;
    const int acol = (tid & 1) << 2;
    const int brow = tid >> 5;
    const int bcol = (tid & 31) << 2;
    const int ty = (tid >> 4) << 3;
    const int tx = (tid & 15) << 3;

    AccT acc[8][8];
#pragma unroll
    for (int i = 0; i < 8; ++i)
#pragma unroll
        for (int j = 0; j < 8; ++j) acc[i][j] = (AccT)0;

    const float* Ap = A + (size_t)(by * 128 + arow) * lda + acol;
    const float* Bp = Bm + (size_t)brow * ldb + bx * 128 + bcol;

    for (int k0 = 0; k0 < K; k0 += 8) {
        float4 av = *(const float4*)(Ap + k0);
        float4 bv = *(const float4*)(Bp + (size_t)k0 * ldb);
        As[acol + 0][arow] = av.x;
        As[acol + 1][arow] = av.y;
        As[acol + 2][arow] = av.z;
        As[acol + 3][arow] = av.w;
        *(float4*)(&Bs[brow][bcol]) = bv;
        __syncthreads();
#pragma unroll
        for (int kk = 0; kk < 8; ++kk) {
            float4 a0 = *(const float4*)(&As[kk][ty]);
            float4 a1 = *(const float4*)(&As[kk][ty + 4]);
            float4 b0 = *(const float4*)(&Bs[kk][tx]);
            float4 b1 = *(const float4*)(&Bs[kk][tx + 4]);
            AccT a[8] = {(AccT)a0.x, (AccT)a0.y, (AccT)a0.z, (AccT)a0.w,
                         (AccT)a1.x, (AccT)a1.y, (AccT)a1.z, (AccT)a1.w};
            AccT b[8] = {(AccT)b0.x, (AccT)b0.y, (AccT)b0.z, (AccT)b0.w,
                         (AccT)b1.x, (AccT)b1.y, (AccT)b1.z, (AccT)b1.w};
#pragma unroll
            for (int i = 0; i < 8; ++i)
#pragma unroll
                for (int j = 0; j < 8; ++j) acc[i][j] += a[i] * b[j];
        }
        __syncthreads();
    }
#pragma unroll
    for (int i = 0; i < 8; ++i) {
        float out[8];
#pragma unroll
        for (int j = 0; j < 8; ++j) out[j] = (float)acc[i][j];
        float* Cp = C + (size_t)(by * 128 + ty + i) * ldc + bx * 128 + tx;
        *(float4*)(Cp) = *(const float4*)(&out[0]);
        *(float4*)(Cp + 4) = *(const float4*)(&out[4]);
    }
}

// ---------------------------------------------------------------------------
// Depthwise temporal conv (width 3) + silu*silu gate.  zg: [8192, 2048]
// (z cols 0..1023, gate cols 1024..2047). zm: [8192,1024], fp32 output.
// Done in fp64 (sign-path fidelity), rounded once.
// ---------------------------------------------------------------------------
__global__ __launch_bounds__(256)
void conv_silu_kernel(const float* __restrict__ zg, const float* __restrict__ dw_w,
                      const float* __restrict__ dw_b, float* __restrict__ zm)
{
    int idx = blockIdx.x * 256 + threadIdx.x;  // 0 .. 8192*1024-1
    int d = idx & 1023;
    int t = idx >> 10;
    int n = t & 4095;
    const float* zrow = zg + (size_t)t * 2048;
    double z0 = (n > 0)    ? (double)zg[(size_t)(t - 1) * 2048 + d] : 0.0;
    double z1 = (double)zrow[d];
    double z2 = (n < 4095) ? (double)zg[(size_t)(t + 1) * 2048 + d] : 0.0;
    double w0 = (double)dw_w[d * 3 + 0];
    double w1 = (double)dw_w[d * 3 + 1];
    double w2 = (double)dw_w[d * 3 + 2];
    double zc = z0 * w0 + z1 * w1 + z2 * w2 + (double)dw_b[d];
    double g  = (double)zrow[1024 + d];
    double sc = zc / (1.0 + exp(-zc));
    double sg = g  / (1.0 + exp(-g));
    zm[idx] = (float)(sc * sg);
}

// ---------------------------------------------------------------------------
// Wb[j][h] = sum_m ge_out_w[j, m] * base_w[m, h]   (fp64; 1024x8)
// Folds qg@base_w into zm@Wb so the sign path skips fp32 qg entirely.
// ---------------------------------------------------------------------------
__global__ __launch_bounds__(256)
void wb_kernel(const float* __restrict__ ge_out_w, const float* __restrict__ base_w,
               double* __restrict__ Wb)
{
    int e = blockIdx.x * 256 + threadIdx.x;  // 0..8191
    int j = e >> 3, h = e & 7;
    const float* wr = ge_out_w + (size_t)j * 2048;
    double s = 0.0;
    for (int m = 0; m < 1024; ++m) s += (double)wr[m] * (double)base_w[m * 8 + h];
    Wb[e] = s;
}

// ---------------------------------------------------------------------------
// Mq = Aq@Bq (64x64); Mkf = (Ak@Bk) * 0.5 * tanh(1+rand_gate[d]) (folds the
// pair-mix 0.5 and the per-channel gate into the k low-rank matrix columns).
// ---------------------------------------------------------------------------
__global__ __launch_bounds__(256)
void lowrank_kernel(const float* __restrict__ Aq, const float* __restrict__ Bq,
                    const float* __restrict__ Ak, const float* __restrict__ Bk,
                    const float* __restrict__ rand_gate,
                    float* __restrict__ Mq, float* __restrict__ Mkf)
{
    int t = threadIdx.x;
    for (int e = t; e < 4096; e += 256) {
        int j = e >> 6, d = e & 63;
        float s1 = 0.f, s2 = 0.f;
#pragma unroll
        for (int r = 0; r < 16; ++r) {
            s1 += Aq[j * 16 + r] * Bq[r * 64 + d];
            s2 += Ak[j * 16 + r] * Bk[r * 64 + d];
        }
        Mq[e] = s1;
        Mkf[e] = s2 * 0.5f * tanhf(1.0f + rand_gate[d]);
    }
}

// ---------------------------------------------------------------------------
// LSH hash: one wave per token. base = zm_row @ Wb (fp64), sim = base @ rot,
// salts XOR by sign(sim), bucket = code & 31.
// ---------------------------------------------------------------------------
__global__ __launch_bounds__(256)
void hash_kernel(const float* __restrict__ zm, const double* __restrict__ Wb,
                 const float* __restrict__ rot, const int* __restrict__ salts,
                 int* __restrict__ bids)
{
    int wave = threadIdx.x >> 6, lane = threadIdx.x & 63;
    int t = blockIdx.x * 4 + wave;
    const float* zrow = zm + (size_t)t * 1024;
    double bacc[8] = {0, 0, 0, 0, 0, 0, 0, 0};
    for (int i = 0; i < 16; ++i) {
        int j = i * 64 + lane;
        double zv = (double)zrow[j];
        const double* wb = Wb + (size_t)j * 8;
#pragma unroll
        for (int h = 0; h < 8; ++h) bacc[h] += zv * wb[h];
    }
#pragma unroll
    for (int h = 0; h < 8; ++h) {
#pragma unroll
        for (int off = 32; off > 0; off >>= 1) bacc[h] += __shfl_xor(bacc[h], off);
    }
    if (lane < 32) {
        int r = lane >> 3, kk = lane & 7;
        double sim = 0.0;
#pragma unroll
        for (int h = 0; h < 8; ++h) sim += bacc[h] * (double)rot[(r * 8 + h) * 8 + kk];
        int m = (sim >= 0.0) ? salts[r * 8 + kk] : 0;
        m ^= __shfl_xor(m, 1);
        m ^= __shfl_xor(m, 2);
        m ^= __shfl_xor(m, 4);
        m ^= __shfl_xor(m, 8);
        m ^= __shfl_xor(m, 16);
        if (lane == 0) bids[t] = m & 31;
    }
}

// ---------------------------------------------------------------------------
// Stable counting sort by bucket id (matches jnp.argsort stable semantics).
// One block per batch; 256 threads x 16 consecutive items each.
// ---------------------------------------------------------------------------
__global__ __launch_bounds__(256)
void sort_kernel(const int* __restrict__ bids, int* __restrict__ order)
{
    __shared__ int counts[256 * 33];
    __shared__ int totals[32];
    __shared__ int bbase[32];
    int b = blockIdx.x, t = threadIdx.x;
    const int* bid = bids + b * 4096;
    int* ord = order + b * 4096;
    int* mycnt = counts + t * 33;
#pragma unroll
    for (int i = 0; i < 33; ++i) mycnt[i] = 0;
    int base_i = t * 16;
    int local[16];
#pragma unroll
    for (int i = 0; i < 16; ++i) {
        local[i] = bid[base_i + i];
        mycnt[local[i]]++;
    }
    __syncthreads();
    if (t < 32) {
        int run = 0;
        for (int c = 0; c < 256; ++c) {
            int v = counts[c * 33 + t];
            counts[c * 33 + t] = run;
            run += v;
        }
        totals[t] = run;
    }
    __syncthreads();
    if (t == 0) {
        int s = 0;
        for (int beta = 0; beta < 32; ++beta) { bbase[beta] = s; s += totals[beta]; }
    }
    __syncthreads();
#pragma unroll
    for (int i = 0; i < 16; ++i) {
        int bb = local[i];
        int pos = bbase[bb] + mycnt[bb];
        mycnt[bb]++;
        ord[pos] = base_i + i;
    }
}

// ---------------------------------------------------------------------------
// In-place per-64-row transform: X[r, :] = X[r, :] @ M  (X: R x 64, M: 64x64)
// One block per 64 rows.
// ---------------------------------------------------------------------------
__global__ __launch_bounds__(256)
void rowmat64_kernel(float* __restrict__ X, const float* __restrict__ M)
{
    __shared__ float Xs[64][65];
    __shared__ __align__(16) float Ms[4096];
    int t = threadIdx.x;
    size_t row0 = (size_t)blockIdx.x * 64;
    {
        int r = t >> 2, cg = (t & 3) * 16;
        const float* xp = X + (row0 + r) * 64 + cg;
#pragma unroll
        for (int q = 0; q < 4; ++q) {
            float4 v = *(const float4*)(xp + q * 4);
            Xs[r][cg + q * 4 + 0] = v.x;
            Xs[r][cg + q * 4 + 1] = v.y;
            Xs[r][cg + q * 4 + 2] = v.z;
            Xs[r][cg + q * 4 + 3] = v.w;
        }
        const float* mp = M + t * 16;
#pragma unroll
        for (int q = 0; q < 4; ++q)
            *(float4*)(&Ms[t * 16 + q * 4]) = *(const float4*)(mp + q * 4);
    }
    __syncthreads();
    int c = t & 63, rg = (t >> 6) * 16;
    for (int rr = 0; rr < 16; ++rr) {
        int r = rg + rr;
        float acc = 0.f;
#pragma unroll
        for (int j = 0; j < 64; ++j) acc += Xs[r][j] * Ms[j * 64 + c];
        X[(row0 + r) * 64 + c] = acc;
    }
}

// ---------------------------------------------------------------------------
// Pair mix: ktm[b, p, c] = e[2i] + s*e[2i+1], p<2048: i=p,s=+1; else i=p-2048,s=-1
// (0.5 and tanh gate already folded into Mkf.)  Layout [8192, 256].
// ---------------------------------------------------------------------------
__global__ __launch_bounds__(256)
void pairmix_kernel(const float* __restrict__ kt0, float* __restrict__ ktm)
{
    int idx = blockIdx.x * 256 + threadIdx.x;  // 0..8192*256-1
    int cfull = idx & 255;
    int t = idx >> 8;
    int p = t & 4095, b = t >> 12;
    int i = (p < 2048) ? p : (p - 2048);
    float sgn = (p < 2048) ? 1.f : -1.f;
    size_t r0 = ((size_t)(b * 4096 + 2 * i)) * 256 + cfull;
    ktm[idx] = kt0[r0] + sgn * kt0[r0 + 256];
}

// ---------------------------------------------------------------------------
// Bucketed attention: one block per (chunk, head, batch). 128 tokens/bucket.
// Threads: 2 per q-row (column halves). K,V staged in LDS (64 KB exactly).
// ---------------------------------------------------------------------------
__global__ __launch_bounds__(256)
void attn_kernel(const float* __restrict__ qt, const float* __restrict__ ktm,
                 const float* __restrict__ v0, const int* __restrict__ order,
                 float* __restrict__ o_tok)
{
    __shared__ __align__(16) float Ks[128][64];
    __shared__ __align__(16) float Vs[128][64];
    const int c = blockIdx.x, h = blockIdx.y, b = blockIdx.z;
    const int t = threadIdx.x;
    const int r = t >> 1, hf = t & 1;
    const int kv = h >> 2;
    const int* ord = order + b * 4096 + c * 128;
    const int tokr = ord[r];
    const size_t rowr = (size_t)b * 4096 + tokr;
    {
        const float* kp = ktm + rowr * 256 + kv * 64 + hf * 32;
        const float* vp = v0 + rowr * 256 + kv * 64 + hf * 32;
#pragma unroll
        for (int q = 0; q < 8; ++q) {
            *(float4*)(&Ks[r][hf * 32 + q * 4]) = *(const float4*)(kp + q * 4);
            *(float4*)(&Vs[r][hf * 32 + q * 4]) = *(const float4*)(vp + q * 4);
        }
    }
    float4 qv[16];
    {
        const float* qp = qt + rowr * 1024 + h * 64;
#pragma unroll
        for (int q = 0; q < 16; ++q) qv[q] = *(const float4*)(qp + q * 4);
    }
    __syncthreads();

    float sc[64];
    float mx = -3.0e38f;
    for (int cc = 0; cc < 64; ++cc) {
        const int col = hf * 64 + cc;
        float sx = 0.f, sy = 0.f, sz = 0.f, sw = 0.f;
#pragma unroll
        for (int q = 0; q < 16; ++q) {
            const float4 k4 = *(const float4*)(&Ks[col][q * 4]);
            sx += qv[q].x * k4.x;
            sy += qv[q].y * k4.y;
            sz += qv[q].z * k4.z;
            sw += qv[q].w * k4.w;
        }
        const float s = (sx + sy + sz + sw) * 0.125f;
        sc[cc] = s;
        mx = fmaxf(mx, s);
    }
    mx = fmaxf(mx, __shfl_xor(mx, 1));
    float lsum = 0.f;
    for (int cc = 0; cc < 64; ++cc) {
        const float e = expf(sc[cc] - mx);
        sc[cc] = e;
        lsum += e;
    }
    lsum += __shfl_xor(lsum, 1);
    const float inv = 1.f / lsum;

    float acc[64];
#pragma unroll
    for (int d = 0; d < 64; ++d) acc[d] = 0.f;
    for (int j = 0; j < 64; ++j) {
        const float p = sc[j];
        const int row = hf * 64 + j;
#pragma unroll
        for (int d4 = 0; d4 < 16; ++d4) {
            const float4 v4 = *(const float4*)(&Vs[row][d4 * 4]);
            acc[d4 * 4 + 0] += p * v4.x;
            acc[d4 * 4 + 1] += p * v4.y;
            acc[d4 * 4 + 2] += p * v4.z;
            acc[d4 * 4 + 3] += p * v4.w;
        }
    }
#pragma unroll
    for (int d = 0; d < 64; ++d) acc[d] += __shfl_xor(acc[d], 1);

    float* op = o_tok + rowr * 1024 + h * 64 + hf * 32;
#pragma unroll
    for (int d4 = 0; d4 < 8; ++d4) {
        float4 o4;
        o4.x = acc[hf * 32 + d4 * 4 + 0] * inv;
        o4.y = acc[hf * 32 + d4 * 4 + 1] * inv;
        o4.z = acc[hf * 32 + d4 * 4 + 2] * inv;
        o4.w = acc[hf * 32 + d4 * 4 + 3] * inv;
        *(float4*)(op + d4 * 4) = o4;
    }
}

// ---------------------------------------------------------------------------
extern "C" void kernel_launch(void* const* d_in, const int* in_sizes, int n_in,
                              void* d_out, int out_size, void* d_ws, size_t ws_size,
                              hipStream_t stream)
{
    const float* x         = (const float*)d_in[0];
    const float* ge_inp_w  = (const float*)d_in[1];
    const float* dw_w      = (const float*)d_in[2];
    const float* dw_b      = (const float*)d_in[3];
    const float* ge_out_w  = (const float*)d_in[4];
    const float* q_w       = (const float*)d_in[5];
    const float* k_w       = (const float*)d_in[6];
    const float* v_w       = (const float*)d_in[7];
    const float* Aq        = (const float*)d_in[8];
    const float* Bq        = (const float*)d_in[9];
    const float* Ak        = (const float*)d_in[10];
    const float* Bk        = (const float*)d_in[11];
    const float* rand_gate = (const float*)d_in[12];
    const float* base_w    = (const float*)d_in[13];
    const float* rot       = (const float*)d_in[14];
    // d_in[15] = u (unused by the reference)
    const float* o_w       = (const float*)d_in[16];
    const int*   salts     = (const int*)d_in[17];

    char* ws = (char*)d_ws;
    float*  zg    = (float*)(ws + 0);            // 8192x2048 ; reused as qgkg, then o_tok
    float*  zm    = (float*)(ws + 67108864);     // 8192x1024 ; reused as q0/qt
    float*  k0    = (float*)(ws + 100663296);    // 8192x256
    float*  v0    = (float*)(ws + 109051904);    // 8192x256
    float*  ktm   = (float*)(ws + 117440512);    // 8192x256
    float*  Mq    = (float*)(ws + 125829120);    // 64x64
    float*  Mkf   = (float*)(ws + 125845504);    // 64x64
    double* Wb    = (double*)(ws + 125861888);   // 1024x8 fp64
    int*    bids  = (int*)(ws + 125927424);      // 8192
    int*    order = (int*)(ws + 125960192);      // 8192
    float*  qgkg  = zg;
    float*  q0    = zm;
    float*  o_tok = zg;
    float*  outp  = (float*)d_out;

    // Small precomputes (independent)
    lowrank_kernel<<<1, 256, 0, stream>>>(Aq, Bq, Ak, Bk, rand_gate, Mq, Mkf);
    wb_kernel<<<32, 256, 0, stream>>>(ge_out_w, base_w, Wb);

    // GEMM1 (fp64 acc, sign path): zg = x @ ge_inp_w   [8192x2048]
    gemm_tile<double><<<dim3(16, 64), 256, 0, stream>>>(x, ge_inp_w, zg, 1024, 1024, 2048, 2048);
    // conv + silu*silu gate -> zm [8192x1024]
    conv_silu_kernel<<<32768, 256, 0, stream>>>(zg, dw_w, dw_b, zm);
    // GEMM2 (fp32): qgkg = zm @ ge_out_w  [8192x2048]  (overwrites zg region)
    gemm_tile<float><<<dim3(16, 64), 256, 0, stream>>>(zm, ge_out_w, qgkg, 1024, 1024, 2048, 2048);
    // hash (fp64 base via Wb fold) -> bids; stable sort -> order
    hash_kernel<<<2048, 256, 0, stream>>>(zm, Wb, rot, salts, bids);
    sort_kernel<<<2, 256, 0, stream>>>(bids, order);
    // q0 = qg @ q_w  [8192x1024] (overwrites zm region; hash already consumed zm)
    gemm_tile<float><<<dim3(8, 64), 256, 0, stream>>>(qgkg, q_w, q0, 1024, 2048, 1024, 1024);
    // q low-rank transform in place (rows of 64 per (token, head))
    rowmat64_kernel<<<2048, 256, 0, stream>>>(q0, Mq);
    // k0 = kg @ k_w [8192x256]; low-rank (+0.5*gate folded) in place; pair mix
    gemm_tile<float><<<dim3(2, 64), 256, 0, stream>>>(qgkg + 1024, k_w, k0, 1024, 2048, 256, 256);
    rowmat64_kernel<<<512, 256, 0, stream>>>(k0, Mkf);
    pairmix_kernel<<<8192, 256, 0, stream>>>(k0, ktm);
    // v0 = x @ v_w [8192x256]
    gemm_tile<float><<<dim3(2, 64), 256, 0, stream>>>(x, v_w, v0, 1024, 1024, 256, 256);
    // bucketed attention -> o_tok [8192x1024] (overwrites qgkg region)
    attn_kernel<<<dim3(32, 16, 2), 256, 0, stream>>>(q0, ktm, v0, order, o_tok);
    // final: out = o_tok @ o_w [8192x1024]
    gemm_tile<float><<<dim3(8, 64), 256, 0, stream>>>(o_tok, o_w, outp, 1024, 1024, 1024, 1024);
}

// Round 2
// 1382.079 us; speedup vs baseline: 1.7304x; 1.7304x over previous
//
#include <hip/hip_runtime.h>
#include <hip/hip_bf16.h>
#include <math.h>

typedef __attribute__((ext_vector_type(8))) short short8;
typedef __attribute__((ext_vector_type(4))) float f32x4;

__device__ inline ushort f2bf(float f) {
    __hip_bfloat16 h = __float2bfloat16(f);
    return *reinterpret_cast<ushort*>(&h);
}

// ---------------------------------------------------------------------------
// fp64-accumulating tiled GEMM (sign path only): C = A @ B, row-major.
// ---------------------------------------------------------------------------
template <typename AccT>
__global__ __launch_bounds__(256)
void gemm_tile(const float* __restrict__ A, const float* __restrict__ Bm,
               float* __restrict__ C, int K, int lda, int ldb, int ldc)
{
    __shared__ float As[8][128];
    __shared__ float Bs[8][128];
    const int tid = threadIdx.x;
    const int bx = blockIdx.x, by = blockIdx.y;
    const int arow = tid >> 1;
    const int acol = (tid & 1) << 2;
    const int brow = tid >> 5;
    const int bcol = (tid & 31) << 2;
    const int ty = (tid >> 4) << 3;
    const int tx = (tid & 15) << 3;

    AccT acc[8][8];
#pragma unroll
    for (int i = 0; i < 8; ++i)
#pragma unroll
        for (int j = 0; j < 8; ++j) acc[i][j] = (AccT)0;

    const float* Ap = A + (size_t)(by * 128 + arow) * lda + acol;
    const float* Bp = Bm + (size_t)brow * ldb + bx * 128 + bcol;

    for (int k0 = 0; k0 < K; k0 += 8) {
        float4 av = *(const float4*)(Ap + k0);
        float4 bv = *(const float4*)(Bp + (size_t)k0 * ldb);
        As[acol + 0][arow] = av.x;
        As[acol + 1][arow] = av.y;
        As[acol + 2][arow] = av.z;
        As[acol + 3][arow] = av.w;
        *(float4*)(&Bs[brow][bcol]) = bv;
        __syncthreads();
#pragma unroll
        for (int kk = 0; kk < 8; ++kk) {
            float4 a0 = *(const float4*)(&As[kk][ty]);
            float4 a1 = *(const float4*)(&As[kk][ty + 4]);
            float4 b0 = *(const float4*)(&Bs[kk][tx]);
            float4 b1 = *(const float4*)(&Bs[kk][tx + 4]);
            AccT a[8] = {(AccT)a0.x, (AccT)a0.y, (AccT)a0.z, (AccT)a0.w,
                         (AccT)a1.x, (AccT)a1.y, (AccT)a1.z, (AccT)a1.w};
            AccT b[8] = {(AccT)b0.x, (AccT)b0.y, (AccT)b0.z, (AccT)b0.w,
                         (AccT)b1.x, (AccT)b1.y, (AccT)b1.z, (AccT)b1.w};
#pragma unroll
            for (int i = 0; i < 8; ++i)
#pragma unroll
                for (int j = 0; j < 8; ++j) acc[i][j] += a[i] * b[j];
        }
        __syncthreads();
    }
#pragma unroll
    for (int i = 0; i < 8; ++i) {
        float out[8];
#pragma unroll
        for (int j = 0; j < 8; ++j) out[j] = (float)acc[i][j];
        float* Cp = C + (size_t)(by * 128 + ty + i) * ldc + bx * 128 + tx;
        *(float4*)(Cp) = *(const float4*)(&out[0]);
        *(float4*)(Cp + 4) = *(const float4*)(&out[4]);
    }
}

// ---------------------------------------------------------------------------
// bf16 MFMA GEMM (m97 structure): C[M,N] = A[M,K] @ B[K,N]
// A: bf16 row-major [M,K] (lda elements); Bt: bf16 [N,K] row-major (ld=K).
// 128x128 block, BK=32, 4 waves (each 64x64 = 4x4 mfma_f32_16x16x32_bf16).
// global_load_lds width-16 staging; OutT = float or __hip_bfloat16.
// ---------------------------------------------------------------------------
__device__ inline void storeC(float v, float* p) { *p = v; }
__device__ inline void storeC(float v, __hip_bfloat16* p) { *p = __float2bfloat16(v); }

template <typename OutT>
__global__ __launch_bounds__(256)
void gemm_mfma_bt(const ushort* __restrict__ A, int lda,
                  const ushort* __restrict__ Bt,
                  OutT* __restrict__ C, int ldc, int K)
{
    __shared__ __attribute__((aligned(16))) ushort As[128 * 32];
    __shared__ __attribute__((aligned(16))) ushort Bs[128 * 32];
    const int tid = threadIdx.x;
    const int wave = tid >> 6, lane = tid & 63;
    const int m0 = blockIdx.y * 128, n0 = blockIdx.x * 128;
    const int wm = (wave >> 1) * 64, wn = (wave & 1) * 64;

    f32x4 acc[4][4] = {};

    // staging geometry: per wave 2 instrs for A (16 rows each) and 2 for B.
    const int r0 = (wave * 2 + 0) * 16 + (lane >> 2);
    const int r1 = (wave * 2 + 1) * 16 + (lane >> 2);
    const int kc = (lane & 3) * 8;  // k-chunk (8 bf16 = 16 B)

    for (int k0 = 0; k0 < K; k0 += 32) {
        const ushort* ga0 = A + (size_t)(m0 + r0) * lda + k0 + kc;
        const ushort* ga1 = A + (size_t)(m0 + r1) * lda + k0 + kc;
        const ushort* gb0 = Bt + (size_t)(n0 + r0) * K + k0 + kc;
        const ushort* gb1 = Bt + (size_t)(n0 + r1) * K + k0 + kc;
        __builtin_amdgcn_global_load_lds(
            (const __attribute__((address_space(1))) unsigned int*)ga0,
            (__attribute__((address_space(3))) unsigned int*)(As + (wave * 2 + 0) * 512),
            16, 0, 0);
        __builtin_amdgcn_global_load_lds(
            (const __attribute__((address_space(1))) unsigned int*)ga1,
            (__attribute__((address_space(3))) unsigned int*)(As + (wave * 2 + 1) * 512),
            16, 0, 0);
        __builtin_amdgcn_global_load_lds(
            (const __attribute__((address_space(1))) unsigned int*)gb0,
            (__attribute__((address_space(3))) unsigned int*)(Bs + (wave * 2 + 0) * 512),
            16, 0, 0);
        __builtin_amdgcn_global_load_lds(
            (const __attribute__((address_space(1))) unsigned int*)gb1,
            (__attribute__((address_space(3))) unsigned int*)(Bs + (wave * 2 + 1) * 512),
            16, 0, 0);
        __syncthreads();

        short8 af[4], bfr[4];
#pragma unroll
        for (int t = 0; t < 4; ++t) {
            af[t]  = *(const short8*)(As + (wm + t * 16 + (lane & 15)) * 32 + (lane >> 4) * 8);
            bfr[t] = *(const short8*)(Bs + (wn + t * 16 + (lane & 15)) * 32 + (lane >> 4) * 8);
        }
#pragma unroll
        for (int i = 0; i < 4; ++i)
#pragma unroll
            for (int j = 0; j < 4; ++j)
                acc[i][j] = __builtin_amdgcn_mfma_f32_16x16x32_bf16(af[i], bfr[j], acc[i][j], 0, 0, 0);
        __syncthreads();
    }

#pragma unroll
    for (int i = 0; i < 4; ++i) {
        const int rowb = m0 + wm + i * 16 + (lane >> 4) * 4;
#pragma unroll
        for (int j = 0; j < 4; ++j) {
            const int col = n0 + wn + j * 16 + (lane & 15);
#pragma unroll
            for (int r = 0; r < 4; ++r)
                storeC(acc[i][j][r], C + (size_t)(rowb + r) * ldc + col);
        }
    }
}

// ---------------------------------------------------------------------------
// conv width-3 + silu*silu (fp64 sign path). Outputs fp32 zm AND bf16 zm.
// ---------------------------------------------------------------------------
__global__ __launch_bounds__(256)
void conv_silu_kernel(const float* __restrict__ zg, const float* __restrict__ dw_w,
                      const float* __restrict__ dw_b, float* __restrict__ zm,
                      __hip_bfloat16* __restrict__ zmb)
{
    int idx = blockIdx.x * 256 + threadIdx.x;
    int d = idx & 1023;
    int t = idx >> 10;
    int n = t & 4095;
    const float* zrow = zg + (size_t)t * 2048;
    double z0 = (n > 0)    ? (double)zg[(size_t)(t - 1) * 2048 + d] : 0.0;
    double z1 = (double)zrow[d];
    double z2 = (n < 4095) ? (double)zg[(size_t)(t + 1) * 2048 + d] : 0.0;
    double w0 = (double)dw_w[d * 3 + 0];
    double w1 = (double)dw_w[d * 3 + 1];
    double w2 = (double)dw_w[d * 3 + 2];
    double zc = z0 * w0 + z1 * w1 + z2 * w2 + (double)dw_b[d];
    double g  = (double)zrow[1024 + d];
    double sc = zc / (1.0 + exp(-zc));
    double sg = g  / (1.0 + exp(-g));
    float r = (float)(sc * sg);
    zm[idx] = r;
    zmb[idx] = __float2bfloat16(r);
}

// ---------------------------------------------------------------------------
// Wb[j][h] = sum_m ge_out_w[j, m] * base_w[m, h]  (fp64; 1024x8)
// ---------------------------------------------------------------------------
__global__ __launch_bounds__(256)
void wb_kernel(const float* __restrict__ ge_out_w, const float* __restrict__ base_w,
               double* __restrict__ Wb)
{
    int e = blockIdx.x * 256 + threadIdx.x;
    int j = e >> 3, h = e & 7;
    const float* wr = ge_out_w + (size_t)j * 2048;
    double s = 0.0;
    for (int m = 0; m < 1024; ++m) s += (double)wr[m] * (double)base_w[m * 8 + h];
    Wb[e] = s;
}

// ---------------------------------------------------------------------------
__global__ __launch_bounds__(256)
void lowrank_kernel(const float* __restrict__ Aq, const float* __restrict__ Bq,
                    const float* __restrict__ Ak, const float* __restrict__ Bk,
                    const float* __restrict__ rand_gate,
                    float* __restrict__ Mq, float* __restrict__ Mkf)
{
    int t = threadIdx.x;
    for (int e = t; e < 4096; e += 256) {
        int j = e >> 6, d = e & 63;
        float s1 = 0.f, s2 = 0.f;
#pragma unroll
        for (int r = 0; r < 16; ++r) {
            s1 += Aq[j * 16 + r] * Bq[r * 64 + d];
            s2 += Ak[j * 16 + r] * Bk[r * 64 + d];
        }
        Mq[e] = s1;
        Mkf[e] = s2 * 0.5f * tanhf(1.0f + rand_gate[d]);
    }
}

// ---------------------------------------------------------------------------
// LSH hash (fp64): base = zm_row @ Wb, sim = base @ rot, bucket id.
// ---------------------------------------------------------------------------
__global__ __launch_bounds__(256)
void hash_kernel(const float* __restrict__ zm, const double* __restrict__ Wb,
                 const float* __restrict__ rot, const int* __restrict__ salts,
                 int* __restrict__ bids)
{
    int wave = threadIdx.x >> 6, lane = threadIdx.x & 63;
    int t = blockIdx.x * 4 + wave;
    const float* zrow = zm + (size_t)t * 1024;
    double bacc[8] = {0, 0, 0, 0, 0, 0, 0, 0};
    for (int i = 0; i < 16; ++i) {
        int j = i * 64 + lane;
        double zv = (double)zrow[j];
        const double* wb = Wb + (size_t)j * 8;
#pragma unroll
        for (int h = 0; h < 8; ++h) bacc[h] += zv * wb[h];
    }
#pragma unroll
    for (int h = 0; h < 8; ++h) {
#pragma unroll
        for (int off = 32; off > 0; off >>= 1) bacc[h] += __shfl_xor(bacc[h], off);
    }
    if (lane < 32) {
        int r = lane >> 3, kk = lane & 7;
        double sim = 0.0;
#pragma unroll
        for (int h = 0; h < 8; ++h) sim += bacc[h] * (double)rot[(r * 8 + h) * 8 + kk];
        int m = (sim >= 0.0) ? salts[r * 8 + kk] : 0;
        m ^= __shfl_xor(m, 1);
        m ^= __shfl_xor(m, 2);
        m ^= __shfl_xor(m, 4);
        m ^= __shfl_xor(m, 8);
        m ^= __shfl_xor(m, 16);
        if (lane == 0) bids[t] = m & 31;
    }
}

// ---------------------------------------------------------------------------
// Stable counting sort by bucket id. One block per batch.
// ---------------------------------------------------------------------------
__global__ __launch_bounds__(256)
void sort_kernel(const int* __restrict__ bids, int* __restrict__ order)
{
    __shared__ int counts[256 * 33];
    __shared__ int totals[32];
    __shared__ int bbase[32];
    int b = blockIdx.x, t = threadIdx.x;
    const int* bid = bids + b * 4096;
    int* ord = order + b * 4096;
    int* mycnt = counts + t * 33;
#pragma unroll
    for (int i = 0; i < 33; ++i) mycnt[i] = 0;
    int base_i = t * 16;
    int local[16];
#pragma unroll
    for (int i = 0; i < 16; ++i) {
        local[i] = bid[base_i + i];
        mycnt[local[i]]++;
    }
    __syncthreads();
    if (t < 32) {
        int run = 0;
        for (int c = 0; c < 256; ++c) {
            int v = counts[c * 33 + t];
            counts[c * 33 + t] = run;
            run += v;
        }
        totals[t] = run;
    }
    __syncthreads();
    if (t == 0) {
        int s = 0;
        for (int beta = 0; beta < 32; ++beta) { bbase[beta] = s; s += totals[beta]; }
    }
    __syncthreads();
#pragma unroll
    for (int i = 0; i < 16; ++i) {
        int bb = local[i];
        int pos = bbase[bb] + mycnt[bb];
        mycnt[bb]++;
        ord[pos] = base_i + i;
    }
}

// ---------------------------------------------------------------------------
// In-place per-64-row transform: X[r, :] = X[r, :] @ M  (64x64)
// ---------------------------------------------------------------------------
__global__ __launch_bounds__(256)
void rowmat64_kernel(float* __restrict__ X, const float* __restrict__ M)
{
    __shared__ float Xs[64][65];
    __shared__ __align__(16) float Ms[4096];
    int t = threadIdx.x;
    size_t row0 = (size_t)blockIdx.x * 64;
    {
        int r = t >> 2, cg = (t & 3) * 16;
        const float* xp = X + (row0 + r) * 64 + cg;
#pragma unroll
        for (int q = 0; q < 4; ++q) {
            float4 v = *(const float4*)(xp + q * 4);
            Xs[r][cg + q * 4 + 0] = v.x;
            Xs[r][cg + q * 4 + 1] = v.y;
            Xs[r][cg + q * 4 + 2] = v.z;
            Xs[r][cg + q * 4 + 3] = v.w;
        }
        const float* mp = M + t * 16;
#pragma unroll
        for (int q = 0; q < 4; ++q)
            *(float4*)(&Ms[t * 16 + q * 4]) = *(const float4*)(mp + q * 4);
    }
    __syncthreads();
    int c = t & 63, rg = (t >> 6) * 16;
    for (int rr = 0; rr < 16; ++rr) {
        int r = rg + rr;
        float acc = 0.f;
#pragma unroll
        for (int j = 0; j < 64; ++j) acc += Xs[r][j] * Ms[j * 64 + c];
        X[(row0 + r) * 64 + c] = acc;
    }
}

// ---------------------------------------------------------------------------
__global__ __launch_bounds__(256)
void pairmix_kernel(const float* __restrict__ kt0, float* __restrict__ ktm)
{
    int idx = blockIdx.x * 256 + threadIdx.x;
    int cfull = idx & 255;
    int t = idx >> 8;
    int p = t & 4095, b = t >> 12;
    int i = (p < 2048) ? p : (p - 2048);
    float sgn = (p < 2048) ? 1.f : -1.f;
    size_t r0 = ((size_t)(b * 4096 + 2 * i)) * 256 + cfull;
    ktm[idx] = kt0[r0] + sgn * kt0[r0 + 256];
}

// ---------------------------------------------------------------------------
// fp32 -> bf16 cast, 4 elements/thread
// ---------------------------------------------------------------------------
__global__ __launch_bounds__(256)
void cast_bf16_kernel(const float4* __restrict__ in, ushort4* __restrict__ out)
{
    int i = blockIdx.x * 256 + threadIdx.x;
    float4 v = in[i];
    ushort4 o;
    o.x = f2bf(v.x); o.y = f2bf(v.y); o.z = f2bf(v.z); o.w = f2bf(v.w);
    out[i] = o;
}

// ---------------------------------------------------------------------------
// B[K,N] fp32 -> Bt[N,K] bf16 (tiled transpose)
// ---------------------------------------------------------------------------
__global__ __launch_bounds__(256)
void transpose_cast_kernel(const float* __restrict__ B, __hip_bfloat16* __restrict__ Bt,
                           int K, int N)
{
    __shared__ float tile[32][33];
    int bx = blockIdx.x, by = blockIdx.y;
    int t = threadIdx.x;
    int tr = t >> 5, tc = t & 31;
#pragma unroll
    for (int p = 0; p < 4; ++p)
        tile[tr + p * 8][tc] = B[(size_t)(by * 32 + tr + p * 8) * N + bx * 32 + tc];
    __syncthreads();
#pragma unroll
    for (int p = 0; p < 4; ++p)
        Bt[(size_t)(bx * 32 + tr + p * 8) * K + by * 32 + tc] =
            __float2bfloat16(tile[tc][tr + p * 8]);
}

// ---------------------------------------------------------------------------
// Bucketed attention; output bf16 (feeds final MFMA GEMM).
// ---------------------------------------------------------------------------
__global__ __launch_bounds__(256)
void attn_kernel(const float* __restrict__ qt, const float* __restrict__ ktm,
                 const float* __restrict__ v0, const int* __restrict__ order,
                 __hip_bfloat16* __restrict__ o_tok)
{
    __shared__ __align__(16) float Ks[128][64];
    __shared__ __align__(16) float Vs[128][64];
    const int c = blockIdx.x, h = blockIdx.y, b = blockIdx.z;
    const int t = threadIdx.x;
    const int r = t >> 1, hf = t & 1;
    const int kv = h >> 2;
    const int* ord = order + b * 4096 + c * 128;
    const int tokr = ord[r];
    const size_t rowr = (size_t)b * 4096 + tokr;
    {
        const float* kp = ktm + rowr * 256 + kv * 64 + hf * 32;
        const float* vp = v0 + rowr * 256 + kv * 64 + hf * 32;
#pragma unroll
        for (int q = 0; q < 8; ++q) {
            *(float4*)(&Ks[r][hf * 32 + q * 4]) = *(const float4*)(kp + q * 4);
            *(float4*)(&Vs[r][hf * 32 + q * 4]) = *(const float4*)(vp + q * 4);
        }
    }
    float4 qv[16];
    {
        const float* qp = qt + rowr * 1024 + h * 64;
#pragma unroll
        for (int q = 0; q < 16; ++q) qv[q] = *(const float4*)(qp + q * 4);
    }
    __syncthreads();

    float sc[64];
    float mx = -3.0e38f;
    for (int cc = 0; cc < 64; ++cc) {
        const int col = hf * 64 + cc;
        float sx = 0.f, sy = 0.f, sz = 0.f, sw = 0.f;
#pragma unroll
        for (int q = 0; q < 16; ++q) {
            const float4 k4 = *(const float4*)(&Ks[col][q * 4]);
            sx += qv[q].x * k4.x;
            sy += qv[q].y * k4.y;
            sz += qv[q].z * k4.z;
            sw += qv[q].w * k4.w;
        }
        const float s = (sx + sy + sz + sw) * 0.125f;
        sc[cc] = s;
        mx = fmaxf(mx, s);
    }
    mx = fmaxf(mx, __shfl_xor(mx, 1));
    float lsum = 0.f;
    for (int cc = 0; cc < 64; ++cc) {
        const float e = expf(sc[cc] - mx);
        sc[cc] = e;
        lsum += e;
    }
    lsum += __shfl_xor(lsum, 1);
    const float inv = 1.f / lsum;

    float acc[64];
#pragma unroll
    for (int d = 0; d < 64; ++d) acc[d] = 0.f;
    for (int j = 0; j < 64; ++j) {
        const float p = sc[j];
        const int row = hf * 64 + j;
#pragma unroll
        for (int d4 = 0; d4 < 16; ++d4) {
            const float4 v4 = *(const float4*)(&Vs[row][d4 * 4]);
            acc[d4 * 4 + 0] += p * v4.x;
            acc[d4 * 4 + 1] += p * v4.y;
            acc[d4 * 4 + 2] += p * v4.z;
            acc[d4 * 4 + 3] += p * v4.w;
        }
    }
#pragma unroll
    for (int d = 0; d < 64; ++d) acc[d] += __shfl_xor(acc[d], 1);

    __hip_bfloat16* op = o_tok + rowr * 1024 + h * 64 + hf * 32;
#pragma unroll
    for (int d = 0; d < 32; ++d)
        op[d] = __float2bfloat16(acc[hf * 32 + d] * inv);
}

// ---------------------------------------------------------------------------
extern "C" void kernel_launch(void* const* d_in, const int* in_sizes, int n_in,
                              void* d_out, int out_size, void* d_ws, size_t ws_size,
                              hipStream_t stream)
{
    const float* x         = (const float*)d_in[0];
    const float* ge_inp_w  = (const float*)d_in[1];
    const float* dw_w      = (const float*)d_in[2];
    const float* dw_b      = (const float*)d_in[3];
    const float* ge_out_w  = (const float*)d_in[4];
    const float* q_w       = (const float*)d_in[5];
    const float* k_w       = (const float*)d_in[6];
    const float* v_w       = (const float*)d_in[7];
    const float* Aq        = (const float*)d_in[8];
    const float* Bq        = (const float*)d_in[9];
    const float* Ak        = (const float*)d_in[10];
    const float* Bk        = (const float*)d_in[11];
    const float* rand_gate = (const float*)d_in[12];
    const float* base_w    = (const float*)d_in[13];
    const float* rot       = (const float*)d_in[14];
    const float* o_w       = (const float*)d_in[16];
    const int*   salts     = (const int*)d_in[17];

    char* ws = (char*)d_ws;
    // Region 0..64MB: zg fp32 (GEMM1 out). After conv_silu, re-partitioned:
    //   qgkg_bf (32MB)@0, x_bf/o_bf (16MB)@32MB, Bt_* (9MB)@48MB
    float*          zg       = (float*)(ws + 0);
    __hip_bfloat16* qgkg_bf  = (__hip_bfloat16*)(ws + 0);
    __hip_bfloat16* xo_bf    = (__hip_bfloat16*)(ws + 33554432);  // x_bf then o_bf
    __hip_bfloat16* Bt_geout = (__hip_bfloat16*)(ws + 50331648);  // 2048x1024 (4MB)
    __hip_bfloat16* Bt_q     = (__hip_bfloat16*)(ws + 54525952);  // 1024x1024 (2MB)
    __hip_bfloat16* Bt_k     = (__hip_bfloat16*)(ws + 56623104);  // 256x1024 (0.5MB)
    __hip_bfloat16* Bt_v     = (__hip_bfloat16*)(ws + 57147392);  // 256x1024 (0.5MB)
    __hip_bfloat16* Bt_o     = (__hip_bfloat16*)(ws + 57671680);  // 1024x1024 (2MB)
    // Region 64..96MB: zm fp32 (hash), then q0 fp32
    float*          zm       = (float*)(ws + 67108864);
    float*          q0       = (float*)(ws + 67108864);
    // Region 96..112MB: zm_bf (16MB), then k0/v0 fp32 (8MB each)
    __hip_bfloat16* zm_bf    = (__hip_bfloat16*)(ws + 100663296);
    float*          k0       = (float*)(ws + 100663296);
    float*          v0       = (float*)(ws + 109051904);
    float*          ktm      = (float*)(ws + 117440512);          // 8MB
    float*          Mq       = (float*)(ws + 125829120);
    float*          Mkf      = (float*)(ws + 125845504);
    double*         Wb       = (double*)(ws + 125861888);
    int*            bids     = (int*)(ws + 125927424);
    int*            order    = (int*)(ws + 125960192);
    float*          outp     = (float*)d_out;

    // Small precomputes
    lowrank_kernel<<<1, 256, 0, stream>>>(Aq, Bq, Ak, Bk, rand_gate, Mq, Mkf);
    wb_kernel<<<32, 256, 0, stream>>>(ge_out_w, base_w, Wb);

    // GEMM1 (fp64 acc, sign path): zg = x @ ge_inp_w  [8192x2048]
    gemm_tile<double><<<dim3(16, 64), 256, 0, stream>>>(x, ge_inp_w, zg, 1024, 1024, 2048, 2048);
    // conv + silu*silu -> zm fp32 (sign) + zm_bf (tolerance). zg dead after.
    conv_silu_kernel<<<32768, 256, 0, stream>>>(zg, dw_w, dw_b, zm, zm_bf);

    // Casts / weight transposes (into freed zg region)
    cast_bf16_kernel<<<8192, 256, 0, stream>>>((const float4*)x, (ushort4*)xo_bf);
    transpose_cast_kernel<<<dim3(64, 32), 256, 0, stream>>>(ge_out_w, Bt_geout, 1024, 2048);
    transpose_cast_kernel<<<dim3(32, 32), 256, 0, stream>>>(q_w, Bt_q, 1024, 1024);
    transpose_cast_kernel<<<dim3(8, 32), 256, 0, stream>>>(k_w, Bt_k, 1024, 256);
    transpose_cast_kernel<<<dim3(8, 32), 256, 0, stream>>>(v_w, Bt_v, 1024, 256);
    transpose_cast_kernel<<<dim3(32, 32), 256, 0, stream>>>(o_w, Bt_o, 1024, 1024);

    // GEMM2 (bf16 MFMA): qgkg_bf = zm_bf @ ge_out_w  [8192x2048], bf16 out
    gemm_mfma_bt<__hip_bfloat16><<<dim3(16, 64), 256, 0, stream>>>(
        (const ushort*)zm_bf, 1024, (const ushort*)Bt_geout, qgkg_bf, 2048, 1024);

    // hash (fp64 sign path, reads zm fp32) -> bids; stable sort -> order
    hash_kernel<<<2048, 256, 0, stream>>>(zm, Wb, rot, salts, bids);
    sort_kernel<<<2, 256, 0, stream>>>(bids, order);

    // q0 = qg @ q_w  [8192x1024] fp32 (overwrites zm; hash already done)
    gemm_mfma_bt<float><<<dim3(8, 64), 256, 0, stream>>>(
        (const ushort*)qgkg_bf, 2048, (const ushort*)Bt_q, q0, 1024, 1024);
    rowmat64_kernel<<<2048, 256, 0, stream>>>(q0, Mq);

    // k0 = kg @ k_w [8192x256] fp32 (overwrites zm_bf; GEMM2 already done)
    gemm_mfma_bt<float><<<dim3(2, 64), 256, 0, stream>>>(
        (const ushort*)(qgkg_bf + 1024), 2048, (const ushort*)Bt_k, k0, 256, 1024);
    rowmat64_kernel<<<512, 256, 0, stream>>>(k0, Mkf);
    pairmix_kernel<<<8192, 256, 0, stream>>>(k0, ktm);

    // v0 = x @ v_w [8192x256] fp32
    gemm_mfma_bt<float><<<dim3(2, 64), 256, 0, stream>>>(
        (const ushort*)xo_bf, 1024, (const ushort*)Bt_v, v0, 256, 1024);

    // bucketed attention -> o_bf (bf16, overwrites x_bf; v0 GEMM done)
    attn_kernel<<<dim3(32, 16, 2), 256, 0, stream>>>(q0, ktm, v0, order, xo_bf);

    // final: out = o @ o_w [8192x1024] fp32
    gemm_mfma_bt<float><<<dim3(8, 64), 256, 0, stream>>>(
        (const ushort*)xo_bf, 1024, (const ushort*)Bt_o, outp, 1024, 1024);
}